// Round 7
// baseline (787.798 us; speedup 1.0000x reference)
//
#include <hip/hip_runtime.h>
#include <hip/hip_bf16.h>
#include <math.h>

typedef __bf16 bf16x8 __attribute__((ext_vector_type(8)));
typedef float f32x4 __attribute__((ext_vector_type(4)));

#define LOG2F 0.6931471805599453f
#define PK1 72     // padded row length (bf16) for K=64 tiles
#define PK2 136    // padded row length (bf16) for K=128 tiles

// fast shifted softplus via hw transcendentals
__device__ __forceinline__ float sspf(float x) {
    float t = __expf(-fabsf(x));
    return fmaxf(x, 0.0f) + __logf(1.0f + t) - LOG2F;
}
// exact f32->bf16 RNE (one-time weight convert)
__device__ __forceinline__ unsigned short f2bf(float f) {
    union { float f; unsigned u; } v; v.f = f;
    unsigned r = v.u + 0x7FFF + ((v.u >> 16) & 1);
    return (unsigned short)(r >> 16);
}
// hw convert for hot paths
__device__ __forceinline__ unsigned short f2bf_fast(float f) {
    __bf16 h = (__bf16)f;
    return __builtin_bit_cast(unsigned short, h);
}

// ---------------- node GEMM (f32, replay-proven in R5) ----------------
template<int ACT>
__global__ void node_gemm(const float* __restrict__ X, const float* __restrict__ W,
                          const float* __restrict__ b, float* __restrict__ Y, int N) {
    __shared__ float xs[2][128];
    const int tid = threadIdx.x;
    const int r = tid >> 7;
    const int c = tid & 127;
    const int row = blockIdx.x * 2 + r;
    if (row < N) xs[r][c] = X[(size_t)row * 128 + c];
    __syncthreads();
    if (row >= N) return;
    float acc = b[c];
#pragma unroll 8
    for (int k = 0; k < 128; ++k)
        acc = fmaf(xs[r][k], W[k * 128 + c], acc);
    if (ACT) acc = tanhf(sspf(acc));
    Y[(size_t)row * 128 + c] = acc;
}

// ---------------- weight pre-convert: W[k][128] f32 -> W^T[n][PK] bf16 ----------------
__global__ void convert_wT(const float* __restrict__ W, unsigned short* __restrict__ O,
                           int K, int PK) {
    int idx = blockIdx.x * 256 + threadIdx.x;
    if (idx >= 128 * PK) return;
    int n = idx / PK, k = idx - n * PK;
    O[idx] = (k < K) ? f2bf(W[k * 128 + n]) : (unsigned short)0;
}

// ---------------- deterministic counting sort by dst ----------------
__global__ void hist_kernel(const int* __restrict__ dst, int* __restrict__ hist, int E) {
    int i = blockIdx.x * 256 + threadIdx.x;
    if (i < E) atomicAdd(&hist[dst[i]], 1);
}
__global__ void scan_kernel(const int* __restrict__ hist, int* __restrict__ row_ptr,
                            int* __restrict__ cursor, int N) {
    __shared__ int part[1024];
    const int tid = threadIdx.x;
    const int chunk = (N + 1023) / 1024;
    const int lo = min(tid * chunk, N);
    const int hi = min(lo + chunk, N);
    int s = 0;
    for (int i = lo; i < hi; ++i) s += hist[i];
    part[tid] = s;
    __syncthreads();
    if (tid == 0) {
        int run = 0;
        for (int i = 0; i < 1024; ++i) { int t = part[i]; part[i] = run; run += t; }
    }
    __syncthreads();
    int run = part[tid];
    for (int i = lo; i < hi; ++i) { row_ptr[i] = run; cursor[i] = run; run += hist[i]; }
}
__global__ void scatter_kernel(const int* __restrict__ dst, int* __restrict__ cursor,
                               int* __restrict__ perm, int E) {
    int i = blockIdx.x * 256 + threadIdx.x;
    if (i < E) { int p = atomicAdd(&cursor[dst[i]], 1); perm[p] = i; }
}
// stabilize: ascending edge-ids within each bucket -> perm is bit-deterministic
__global__ void sort_buckets(const int* __restrict__ row_ptr, const int* __restrict__ hist,
                             int* __restrict__ perm, int N) {
    int n = blockIdx.x * 256 + threadIdx.x;
    if (n >= N) return;
    const int lo = row_ptr[n], hi = lo + hist[n];
    for (int i = lo + 1; i < hi; ++i) {
        int v = perm[i]; int j = i - 1;
        while (j >= lo && perm[j] > v) { perm[j + 1] = perm[j]; --j; }
        perm[j + 1] = v;
    }
}
__global__ void permute_sd(const int* __restrict__ perm, const int* __restrict__ src,
                           const int* __restrict__ dst, int* __restrict__ srcP,
                           int* __restrict__ dstP, int E) {
    int i = blockIdx.x * 256 + threadIdx.x;
    if (i < E) { int e = perm[i]; srcP[i] = src[e]; dstP[i] = dst[e]; }
}
__global__ void permute_e(const int* __restrict__ perm, const float* __restrict__ Ef,
                          unsigned short* __restrict__ Ebf, int nE) {
    long long idx = (long long)blockIdx.x * 256 + threadIdx.x;
    if (idx >= (long long)nE * 16) return;
    int p = (int)(idx >> 4), q = (int)(idx & 15);
    int e = perm[p];
    float4 v = *(const float4*)&Ef[(size_t)e * 64 + q * 4];
    unsigned short* o = &Ebf[(size_t)p * 64 + q * 4];
    o[0] = f2bf_fast(v.x); o[1] = f2bf_fast(v.y);
    o[2] = f2bf_fast(v.z); o[3] = f2bf_fast(v.w);
}

// ---------------- fused edge MLP + gather/filter + merged-atomic scatter ----------------
// MODE 0: Ebf = sorted bf16 edge features (contiguous). MODE 1: stage from f32 Ef via perm.
template<int MODE>
__global__ __launch_bounds__(256) void edge_mfma(
    const unsigned short* __restrict__ Ebf, const float* __restrict__ Ef,
    const int* __restrict__ perm,
    const int* __restrict__ srcA, const int* __restrict__ dstA,
    const float* __restrict__ HV,
    const unsigned short* __restrict__ W1T, const float* __restrict__ b1,
    const unsigned short* __restrict__ W2T, const float* __restrict__ b2,
    float* __restrict__ AGG, int nE)
{
    __shared__ unsigned short sT1[64 * PK2];
    __shared__ int sSrc[64], sDst[64];
    __shared__ unsigned short sE[(MODE == 1) ? 64 * PK1 : 4];

    const int tid = threadIdx.x;
    const int e0 = blockIdx.x * 64;

    if (tid < 64) {
        int gi = min(e0 + tid, nE - 1);
        sSrc[tid] = srcA[gi];
        sDst[tid] = dstA[gi];
    }
    if (MODE == 1) {
        const int r = tid >> 2, c0 = (tid & 3) * 16;
        int gi = e0 + r;
        int e = (gi < nE) ? (perm ? perm[gi] : gi) : 0;
        const float4* s4 = (const float4*)&Ef[(size_t)e * 64 + c0];
        unsigned short* dr = &sE[r * PK1 + c0];
#pragma unroll
        for (int j = 0; j < 4; ++j) {
            float4 v = s4[j];
            dr[j*4+0] = f2bf_fast(v.x); dr[j*4+1] = f2bf_fast(v.y);
            dr[j*4+2] = f2bf_fast(v.z); dr[j*4+3] = f2bf_fast(v.w);
        }
    }
    __syncthreads();   // covers sSrc/sDst (+ sE in MODE 1)

    const int w = tid >> 6, l = tid & 63, cb = w * 32, lr = l & 15, hi = l >> 4, lk = hi * 8;
    const float bb1[2] = { b1[cb + lr], b1[cb + 16 + lr] };
    const float bb2[2] = { b2[cb + lr], b2[cb + 16 + lr] };

    bf16x8 B1[2][2];
#pragma unroll
    for (int nt = 0; nt < 2; ++nt)
#pragma unroll
        for (int kt = 0; kt < 2; ++kt)
            B1[nt][kt] = *(const bf16x8*)&W1T[(size_t)(cb + nt*16 + lr) * PK1 + kt*32 + lk];

    // GEMM1: T1 = ssp(E @ W1 + b1)
    f32x4 acc1[4][2];
#pragma unroll
    for (int mt = 0; mt < 4; ++mt)
#pragma unroll
        for (int nt = 0; nt < 2; ++nt)
            acc1[mt][nt] = (f32x4){bb1[nt], bb1[nt], bb1[nt], bb1[nt]};
#pragma unroll
    for (int kt = 0; kt < 2; ++kt)
#pragma unroll
        for (int mt = 0; mt < 4; ++mt) {
            bf16x8 A;
            if (MODE == 0) {
                const int row = min(e0 + mt*16 + lr, nE - 1);
                A = *(const bf16x8*)&Ebf[(size_t)row * 64 + kt*32 + lk];
            } else {
                A = *(const bf16x8*)&sE[(mt*16 + lr) * PK1 + kt*32 + lk];
            }
#pragma unroll
            for (int nt = 0; nt < 2; ++nt)
                acc1[mt][nt] = __builtin_amdgcn_mfma_f32_16x16x32_bf16(A, B1[nt][kt], acc1[mt][nt], 0, 0, 0);
        }

#pragma unroll
    for (int mt = 0; mt < 4; ++mt)
#pragma unroll
        for (int nt = 0; nt < 2; ++nt) {
            const int col = cb + nt*16 + lr;
#pragma unroll
            for (int r = 0; r < 4; ++r) {
                const int row = mt*16 + hi*4 + r;
                sT1[row * PK2 + col] = f2bf_fast(sspf(acc1[mt][nt][r]));
            }
        }
    __syncthreads();

    bf16x8 B2[2][4];
#pragma unroll
    for (int nt = 0; nt < 2; ++nt)
#pragma unroll
        for (int kt = 0; kt < 4; ++kt)
            B2[nt][kt] = *(const bf16x8*)&W2T[(size_t)(cb + nt*16 + lr) * PK2 + kt*32 + lk];

    // GEMM2: he = ssp(T1 @ W2 + b2)
    f32x4 acc2[4][2];
#pragma unroll
    for (int mt = 0; mt < 4; ++mt)
#pragma unroll
        for (int nt = 0; nt < 2; ++nt)
            acc2[mt][nt] = (f32x4){bb2[nt], bb2[nt], bb2[nt], bb2[nt]};
#pragma unroll
    for (int kt = 0; kt < 4; ++kt)
#pragma unroll
        for (int mt = 0; mt < 4; ++mt) {
            bf16x8 A = *(const bf16x8*)&sT1[(mt*16 + lr) * PK2 + kt*32 + lk];
#pragma unroll
            for (int nt = 0; nt < 2; ++nt)
                acc2[mt][nt] = __builtin_amdgcn_mfma_f32_16x16x32_bf16(A, B2[nt][kt], acc2[mt][nt], 0, 0, 0);
        }

    // epilogue: msg = hv[src]*ssp(acc2); run-length merge (correct for any dst order)
    const int col0 = cb + lr, col1 = cb + 16 + lr;
    int curd = sDst[hi * 4];
    float s0 = 0.f, s1 = 0.f;
#pragma unroll
    for (int mt = 0; mt < 4; ++mt) {
#pragma unroll
        for (int r = 0; r < 4; ++r) {
            const int row = mt*16 + hi*4 + r;
            const float msk = (e0 + row < nE) ? 1.f : 0.f;
            const float he0 = sspf(acc2[mt][0][r]) * msk;
            const float he1 = sspf(acc2[mt][1][r]) * msk;
            const int s = sSrc[row], d = sDst[row];
            const float m0 = HV[(size_t)s * 128 + col0] * he0;
            const float m1 = HV[(size_t)s * 128 + col1] * he1;
            if (d != curd) {
                atomicAdd(&AGG[(size_t)curd * 128 + col0], s0);
                atomicAdd(&AGG[(size_t)curd * 128 + col1], s1);
                s0 = 0.f; s1 = 0.f; curd = d;
            }
            s0 += m0; s1 += m1;
        }
    }
    atomicAdd(&AGG[(size_t)curd * 128 + col0], s0);
    atomicAdd(&AGG[(size_t)curd * 128 + col1], s1);
}

extern "C" void kernel_launch(void* const* d_in, const int* in_sizes, int n_in,
                              void* d_out, int out_size, void* d_ws, size_t ws_size,
                              hipStream_t stream) {
    const float* x    = (const float*)d_in[0];
    const float* e    = (const float*)d_in[1];
    const int*   src  = (const int*)  d_in[2];
    const int*   dst  = (const int*)  d_in[3];
    const float* n1W  = (const float*)d_in[4];
    const float* n1b  = (const float*)d_in[5];
    const float* e1W1 = (const float*)d_in[6];
    const float* e1b1 = (const float*)d_in[7];
    const float* e1W2 = (const float*)d_in[8];
    const float* e1b2 = (const float*)d_in[9];
    const float* o1W  = (const float*)d_in[10];
    const float* o1b  = (const float*)d_in[11];
    const float* n2W  = (const float*)d_in[12];
    const float* n2b  = (const float*)d_in[13];
    const float* e2W1 = (const float*)d_in[14];
    const float* e2b1 = (const float*)d_in[15];
    const float* e2W2 = (const float*)d_in[16];
    const float* e2b2 = (const float*)d_in[17];
    const float* o2W  = (const float*)d_in[18];
    const float* o2b  = (const float*)d_in[19];

    const int N = in_sizes[0] / 128;
    const int E = in_sizes[2];
    float* out = (float*)d_out;

    char* ws = (char*)d_ws;
    size_t off = 0;
    auto alloc = [&](size_t bytes) -> char* {
        char* p = ws + off;
        off = (off + bytes + 255) & ~(size_t)255;
        return p;
    };
    float* agg = (float*)alloc((size_t)N * 128 * 4);
    float* hv  = (float*)alloc((size_t)N * 128 * 4);
    unsigned short* w_e1w1 = (unsigned short*)alloc(128 * PK1 * 2);
    unsigned short* w_e1w2 = (unsigned short*)alloc(128 * PK2 * 2);
    unsigned short* w_e2w1 = (unsigned short*)alloc(128 * PK1 * 2);
    unsigned short* w_e2w2 = (unsigned short*)alloc(128 * PK2 * 2);
    int* perm    = (int*)alloc((size_t)E * 4);
    int* srcP    = (int*)alloc((size_t)E * 4);
    int* dstP    = (int*)alloc((size_t)E * 4);
    int* hist    = (int*)alloc((size_t)N * 4);
    int* cursor  = (int*)alloc((size_t)N * 4);
    int* row_ptr = (int*)alloc((size_t)N * 4);
    const size_t sort_need = off;
    unsigned short* Ebf = (unsigned short*)alloc((size_t)E * 64 * 2);
    const bool useEbf  = (ws_size >= off);
    const bool useSort = (ws_size >= sort_need);

    float* hbuf = out;   // layer-1 hidden lives in d_out (fully rewritten before final output)

    // edge-weight converts
    convert_wT<<<(128*PK1 + 255)/256, 256, 0, stream>>>(e1W1, w_e1w1, 64,  PK1);
    convert_wT<<<(128*PK2 + 255)/256, 256, 0, stream>>>(e1W2, w_e1w2, 128, PK2);
    convert_wT<<<(128*PK1 + 255)/256, 256, 0, stream>>>(e2W1, w_e2w1, 64,  PK1);
    convert_wT<<<(128*PK2 + 255)/256, 256, 0, stream>>>(e2W2, w_e2w2, 128, PK2);

    const int* sA = src;
    const int* dA = dst;
    const int* permArg = nullptr;
    if (useSort) {
        hipMemsetAsync(hist, 0, (size_t)N * 4, stream);
        hist_kernel<<<(E + 255)/256, 256, 0, stream>>>(dst, hist, E);
        scan_kernel<<<1, 1024, 0, stream>>>(hist, row_ptr, cursor, N);
        scatter_kernel<<<(E + 255)/256, 256, 0, stream>>>(dst, cursor, perm, E);
        sort_buckets<<<(N + 255)/256, 256, 0, stream>>>(row_ptr, hist, perm, N);
        permute_sd<<<(E + 255)/256, 256, 0, stream>>>(perm, src, dst, srcP, dstP, E);
        if (useEbf)
            permute_e<<<(int)(((size_t)E * 16 + 255)/256), 256, 0, stream>>>(perm, e, Ebf, E);
        sA = srcP; dA = dstP; permArg = perm;
    }

    const int nodeBlocks = (N + 1) / 2;
    const int edgeBlocks = (E + 63) / 64;
    const size_t nbytes = (size_t)N * 128 * 4;

    // ---- layer 1 ----
    node_gemm<0><<<nodeBlocks, 256, 0, stream>>>(x, n1W, n1b, hv, N);
    hipMemsetAsync(agg, 0, nbytes, stream);
    if (useEbf)
        edge_mfma<0><<<edgeBlocks, 256, 0, stream>>>(Ebf, nullptr, nullptr, sA, dA, hv,
                                                     w_e1w1, e1b1, w_e1w2, e1b2, agg, E);
    else
        edge_mfma<1><<<edgeBlocks, 256, 0, stream>>>(nullptr, e, permArg, sA, dA, hv,
                                                     w_e1w1, e1b1, w_e1w2, e1b2, agg, E);
    node_gemm<1><<<nodeBlocks, 256, 0, stream>>>(agg, o1W, o1b, hbuf, N);

    // ---- layer 2 ----
    node_gemm<0><<<nodeBlocks, 256, 0, stream>>>(hbuf, n2W, n2b, hv, N);
    hipMemsetAsync(agg, 0, nbytes, stream);
    if (useEbf)
        edge_mfma<0><<<edgeBlocks, 256, 0, stream>>>(Ebf, nullptr, nullptr, sA, dA, hv,
                                                     w_e2w1, e2b1, w_e2w2, e2b2, agg, E);
    else
        edge_mfma<1><<<edgeBlocks, 256, 0, stream>>>(nullptr, e, permArg, sA, dA, hv,
                                                     w_e2w1, e2b1, w_e2w2, e2b2, agg, E);
    node_gemm<1><<<nodeBlocks, 256, 0, stream>>>(agg, o2W, o2b, out, N);
}